// Round 7
// baseline (32486.169 us; speedup 1.0000x reference)
//
#include <hip/hip_runtime.h>
#include <hip/hip_bf16.h>
#include <cstddef>

#define NN 32768
#define BM 64
#define BN 64
#define BK 32

typedef float f32x4 __attribute__((ext_vector_type(4)));
typedef short short8 __attribute__((ext_vector_type(8)));

__device__ inline unsigned short f2bf(float f) {
    unsigned u = __builtin_bit_cast(unsigned, f);
    unsigned r = (u + 0x7FFFu + ((u >> 16) & 1u)) >> 16;
    return (unsigned short)r;
}
__device__ inline float tanh_f(float x) {
    float e = __expf(-2.f * x);
    return 2.f * __builtin_amdgcn_rcpf(1.f + e) - 1.f;
}

// Gate-interleave permutation: permuted position p = w*64 + nt*16 + u'
// (w = wave, nt = gate index i/f/g/o, u' = unit-in-wave) maps to original
// gate row nt*128 + w*16 + u'.
__device__ inline int permrow(int p) {
    return ((p >> 4) & 3) * 128 + ((p >> 6) << 4) + (p & 15);
}

// Generic fp32 GEMM: C[M,N] = concat(A1[idx],A2[idx]) @ W[N,K].T + b1 (+ b2)
// permW: output column gc uses W row permrow(gc) and bias permrow(gc).
__global__ __launch_bounds__(256) void gemm_cat(
    const float* __restrict__ A1, const int* __restrict__ idx1,
    const float* __restrict__ A2, const int* __restrict__ idx2, int istr,
    int K1, int K2,
    const float* __restrict__ W, const float* __restrict__ b1,
    const float* __restrict__ b2, int permW,
    float* __restrict__ C, int M, int N)
{
    const int K = K1 + K2;
    __shared__ __align__(16) float As[BK][BM + 4];  // [k][m]
    __shared__ __align__(16) float Ws[BK][BN + 4];  // [k][n]
    const int tid = threadIdx.x;
    const int m0 = blockIdx.x * BM;
    const int n0 = blockIdx.y * BN;
    const int tx = tid & 15;
    const int ty = tid >> 4;
    float acc[4][4] = {};

    for (int k0 = 0; k0 < K; k0 += BK) {
        #pragma unroll
        for (int p = 0; p < 2; ++p) {
            int q = tid + p * 256;
            int row = q >> 3;
            int kq = (q & 7) * 4;
            int gk = k0 + kq;
            int grow = m0 + row;
            const float* src;
            if (gk < K1) {
                int r = idx1 ? idx1[grow * istr] : grow;
                src = A1 + (size_t)r * K1 + gk;
            } else {
                int r = idx2 ? idx2[grow * istr] : grow;
                src = A2 + (size_t)r * K2 + (gk - K1);
            }
            float4 v = *(const float4*)src;
            As[kq + 0][row] = v.x; As[kq + 1][row] = v.y;
            As[kq + 2][row] = v.z; As[kq + 3][row] = v.w;
        }
        #pragma unroll
        for (int p = 0; p < 2; ++p) {
            int q = tid + p * 256;
            int row = q >> 3;
            int kq = (q & 7) * 4;
            int wrow = n0 + row;
            if (permW) wrow = permrow(wrow);
            const float* src = W + (size_t)wrow * K + (k0 + kq);
            float4 v = *(const float4*)src;
            Ws[kq + 0][row] = v.x; Ws[kq + 1][row] = v.y;
            Ws[kq + 2][row] = v.z; Ws[kq + 3][row] = v.w;
        }
        __syncthreads();
        #pragma unroll
        for (int kk = 0; kk < BK; ++kk) {
            float4 a = *(const float4*)&As[kk][ty * 4];
            float4 b = *(const float4*)&Ws[kk][tx * 4];
            float av[4] = {a.x, a.y, a.z, a.w};
            float bv[4] = {b.x, b.y, b.z, b.w};
            #pragma unroll
            for (int i = 0; i < 4; ++i)
                #pragma unroll
                for (int jj = 0; jj < 4; ++jj)
                    acc[i][jj] += av[i] * bv[jj];
        }
        __syncthreads();
    }
    #pragma unroll
    for (int i = 0; i < 4; ++i) {
        int gr = m0 + ty * 4 + i;
        #pragma unroll
        for (int jj = 0; jj < 4; ++jj) {
            int gc = n0 + tx * 4 + jj;
            int bi = permW ? permrow(gc) : gc;
            float bias = b1 ? b1[bi] : 0.f;
            if (b2) bias += b2[bi];
            C[(size_t)gr * N + gc] = acc[i][jj] + bias;
        }
    }
}

// Barrier that drains only LDS ops (not the hs global store / xg prefetch
// loads, which __syncthreads' vmcnt(0) would wait on every step). Single
// asm block => nothing schedules between the wait and the barrier.
#define LDS_BARRIER() asm volatile("s_waitcnt lgkmcnt(0)\n\ts_barrier" ::: "memory")

// MFMA LSTM scan, operand-swapped + GATE-SPLIT activations.
// 8 waves; wave w owns units w*16..+15; lane (grp,m): D col m = unit,
// rows replicated. Round-6 counters: VALUBusy/CU 48% + MfmaUtil/CU 47%,
// serialized -> cut VALU. Each lane now activates ONLY gate grp
// (grp0=i, 1=f, 2=g(tanh), 3=o), then 3 shuffles (xor16, 2x xor32)
// redistribute all 4 gates to every replica; all lanes run the c/h chain
// redundantly (bit-identical across replicas). Trans/wave: 10 -> 4.
// xg: each lane loads only its own gate's value (1 load vs 4); acc[nt][0]
// all init to that one value (only acc[grp][0] is ever read; others rot
// like elements 1..3 -- bounded random walk, fp32-safe, never read).
__global__ __launch_bounds__(512)
__attribute__((amdgpu_waves_per_eu(2, 2)))
void lstm_scan(const float* __restrict__ xg,    // [T, 512] permuted layout
               const float* __restrict__ Whh,   // [512, 128] fp32 original
               float* __restrict__ hs,          // [T, 128] fp32
               int T)
{
    __shared__ __align__(16) unsigned short hbuf[2][128];  // h in bf16
    const int tid  = threadIdx.x;
    const int w    = tid >> 6;
    const int lane = tid & 63;
    const int m    = lane & 15;   // unit-in-wave (D column)
    const int grp  = lane >> 4;   // replica group = owned gate index

    // B fragments: gate tile nt, k-tile kt:
    // B[k = kt*32+grp*8+j][col = m] = Whh[nt*128 + w*16 + m][kt*32+grp*8+j]
    short8 wfrag[4][4];
    #pragma unroll
    for (int nt = 0; nt < 4; ++nt)
        #pragma unroll
        for (int kt = 0; kt < 4; ++kt) {
            const float* src = Whh + (size_t)(nt * 128 + w * 16 + m) * 128
                                   + kt * 32 + grp * 8;
            f32x4 v0 = *(const f32x4*)src;
            f32x4 v1 = *(const f32x4*)(src + 4);
            short8 s;
            s[0] = (short)f2bf(v0[0]); s[1] = (short)f2bf(v0[1]);
            s[2] = (short)f2bf(v0[2]); s[3] = (short)f2bf(v0[3]);
            s[4] = (short)f2bf(v1[0]); s[5] = (short)f2bf(v1[1]);
            s[6] = (short)f2bf(v1[2]); s[7] = (short)f2bf(v1[3]);
            wfrag[nt][kt] = s;
        }

    if (tid < 128) { hbuf[0][tid] = 0; hbuf[1][tid] = 0; }

    // own-gate xg position: gate grp of unit w*16+m = permuted w*64+grp*16+m
    const int xoff = w * 64 + grp * 16 + m;
    float xcA = xg[xoff];                      // step 0
    float xcB = xg[512 + xoff];                // step 1
    const float* xpre = xg + 2 * 512 + xoff;   // prefetch base (step t+2)
    float* hsp = hs + w * 16 + m;              // store base (grp==0 lanes)
    float c = 0.f;
    f32x4 acc[4];
    #pragma unroll
    for (int nt = 0; nt < 4; ++nt) acc[nt] = (f32x4){0.f, 0.f, 0.f, 0.f};

    const bool isg    = (grp == 2);            // tanh gate
    const bool hiGrp  = (grp >= 2);
    const bool oddGrp = (grp & 1);
    const float amul  = isg ? 2.f : 1.f;       // tanh(x) = 2*sigmoid(2x)-1
    __syncthreads();

    for (int t = 0; t < T; t += 2) {
        // ================ even sub-step (t): read hbuf[0] -> write hbuf[1]
        {
            short8 hfrag[4];
            #pragma unroll
            for (int kt = 0; kt < 4; ++kt)
                hfrag[kt] = *(const short8*)&hbuf[0][kt * 32 + grp * 8];

            #pragma unroll
            for (int nt = 0; nt < 4; ++nt) acc[nt][0] = xcA;  // broadcast

            if (t + 2 < T) xcA = xpre[0];      // prefetch xg[t+2] (own gate)

            #pragma unroll
            for (int kt = 0; kt < 4; ++kt)   // kt outer: 4 interleaved chains
                #pragma unroll
                for (int nt = 0; nt < 4; ++nt)
                    acc[nt] = __builtin_amdgcn_mfma_f32_16x16x32_bf16(
                        hfrag[kt], wfrag[nt][kt], acc[nt], 0, 0, 0);

            // own gate: grp0=acc[0], 1=acc[1], 2=acc[2], 3=acc[3]
            float e01 = oddGrp ? acc[1][0] : acc[0][0];
            float e23 = oddGrp ? acc[3][0] : acc[2][0];
            float gown = hiGrp ? e23 : e01;
            float ee = __expf(-amul * gown);
            float ss = __builtin_amdgcn_rcpf(1.f + ee);
            float act = isg ? 2.f * ss - 1.f : ss;

            // redistribute: xor16 pairs (i<->f, g<->o), xor32 crosses halves
            float p16 = __shfl_xor(act, 16);
            float lo = oddGrp ? p16 : act;     // iv (grp01) / gv (grp23)
            float hi = oddGrp ? act : p16;     // fv / ov
            float lo2 = __shfl_xor(lo, 32);
            float hi2 = __shfl_xor(hi, 32);
            float iv = hiGrp ? lo2 : lo;
            float gv = hiGrp ? lo  : lo2;
            float fv = hiGrp ? hi2 : hi;
            float ov = hiGrp ? hi  : hi2;

            c = fv * c + iv * gv;
            float h = ov * tanh_f(c);

            if (grp == 0) {
                hbuf[1][w * 16 + m] = f2bf(h);
                hsp[0] = h;
            }
            LDS_BARRIER();
        }
        // ================ odd sub-step (t+1): read hbuf[1] -> write hbuf[0]
        {
            short8 hfrag[4];
            #pragma unroll
            for (int kt = 0; kt < 4; ++kt)
                hfrag[kt] = *(const short8*)&hbuf[1][kt * 32 + grp * 8];

            #pragma unroll
            for (int nt = 0; nt < 4; ++nt) acc[nt][0] = xcB;

            if (t + 3 < T) xcB = xpre[512];

            #pragma unroll
            for (int kt = 0; kt < 4; ++kt)
                #pragma unroll
                for (int nt = 0; nt < 4; ++nt)
                    acc[nt] = __builtin_amdgcn_mfma_f32_16x16x32_bf16(
                        hfrag[kt], wfrag[nt][kt], acc[nt], 0, 0, 0);

            float e01 = oddGrp ? acc[1][0] : acc[0][0];
            float e23 = oddGrp ? acc[3][0] : acc[2][0];
            float gown = hiGrp ? e23 : e01;
            float ee = __expf(-amul * gown);
            float ss = __builtin_amdgcn_rcpf(1.f + ee);
            float act = isg ? 2.f * ss - 1.f : ss;

            float p16 = __shfl_xor(act, 16);
            float lo = oddGrp ? p16 : act;
            float hi = oddGrp ? act : p16;
            float lo2 = __shfl_xor(lo, 32);
            float hi2 = __shfl_xor(hi, 32);
            float iv = hiGrp ? lo2 : lo;
            float gv = hiGrp ? lo  : lo2;
            float fv = hiGrp ? hi2 : hi;
            float ov = hiGrp ? hi  : hi2;

            c = fv * c + iv * gv;
            float h = ov * tanh_f(c);

            if (grp == 0) {
                hbuf[0][w * 16 + m] = f2bf(h);
                hsp[128] = h;
            }
            LDS_BARRIER();
        }
        xpre += 1024;
        hsp  += 256;
    }
}

extern "C" void kernel_launch(void* const* d_in, const int* in_sizes, int n_in,
                              void* d_out, int out_size, void* d_ws, size_t ws_size,
                              hipStream_t stream) {
    const float* inputs = (const float*)d_in[0];
    const int*   edges  = (const int*)d_in[1];     // [N,2] int32
    const float* in_W   = (const float*)d_in[2];   // [128,128]
    const float* in_b   = (const float*)d_in[3];   // [128]
    const float* out_W  = (const float*)d_in[4];   // [128,128]
    const float* out_b  = (const float*)d_in[5];   // [128]
    const float* edge_W = (const float*)d_in[6];   // [2,128,256]
    const float* edge_b = (const float*)d_in[7];   // [2,128]
    const float* Wih    = (const float*)d_in[8];   // [2,512,256]
    const float* Whh    = (const float*)d_in[9];   // [2,512,128]
    const float* bih    = (const float*)d_in[10];  // [2,512]
    const float* bhh    = (const float*)d_in[11];  // [2,512]
    float* out = (float*)d_out;

    float* ws = (float*)d_ws;
    float* nodesA = ws;                          // 32768*128
    float* nodesB = nodesA + (size_t)NN * 128;   // 32768*128
    float* edge_h = nodesB + (size_t)NN * 128;   // 32768*128
    float* xgbuf  = edge_h + (size_t)NN * 128;   // 32768*512

    dim3 blk(256);
    dim3 g128(NN / BM, 128 / BN);
    dim3 g512(NN / BM, 512 / BN);

    // nodes = inputs @ in_W.T + in_b
    gemm_cat<<<g128, blk, 0, stream>>>(inputs, nullptr, nullptr, nullptr, 1,
                                       128, 0, in_W, in_b, nullptr, 0,
                                       nodesA, NN, 128);

    const float* cur = nodesA;
    float* nxt = nodesB;
    for (int r = 0; r < 2; ++r) {
        // edge_h = concat(nodes[src], nodes[dst]) @ edge_W[r].T + edge_b[r]
        gemm_cat<<<g128, blk, 0, stream>>>(cur, edges + 0, cur, edges + 1, 2,
                                           128, 128,
                                           edge_W + (size_t)r * 128 * 256,
                                           edge_b + (size_t)r * 128, nullptr, 0,
                                           edge_h, NN, 128);
        // xg = concat(inputs, edge_h) @ Wih[r].T + bih[r] + bhh[r], PERMUTED
        gemm_cat<<<g512, blk, 0, stream>>>(inputs, nullptr, edge_h, nullptr, 1,
                                           128, 128,
                                           Wih + (size_t)r * 512 * 256,
                                           bih + (size_t)r * 512,
                                           bhh + (size_t)r * 512, 1,
                                           xgbuf, NN, 512);
        // sequential LSTM scan (MFMA, operand-swapped, gate-split)
        lstm_scan<<<1, 512, 0, stream>>>(xgbuf, Whh + (size_t)r * 512 * 128,
                                         nxt, NN);
        const float* tmp = cur;
        cur = nxt;
        nxt = (float*)tmp;
    }

    // out = nodes @ out_W.T + out_b
    gemm_cat<<<g128, blk, 0, stream>>>(cur, nullptr, nullptr, nullptr, 1,
                                       128, 0, out_W, out_b, nullptr, 0,
                                       out, NN, 128);
}